// Round 3
// baseline (55.719 us; speedup 1.0000x reference)
//
#include <hip/hip_runtime.h>
#include <hip/hip_bf16.h>

#define BS  32
#define J   4
#define L   512
#define D   768
#define K   4
#define OUT 256
// sentence = b*J + j (128 total); global entity index = sentence*K + k
// (matches reference reshape: e = b*16 + j*4 + k)

__global__ __launch_bounds__(1024) void entity_fused_kernel(
    const float* __restrict__ Z,     // [BS, J, L, D]
    const int*   __restrict__ sep,   // [BS, J, K]
    const float* __restrict__ W,     // [D, OUT]
    const float* __restrict__ bias,  // [OUT]
    float*       __restrict__ out)   // [BS*J*K, OUT]
{
    const int sent = blockIdx.x;     // 0..127
    const int tid  = threadIdx.x;    // 0..1023
    const int s    = tid >> 8;       // token stripe 0..3
    const int t    = tid & 255;      // dim lane: owns dims t, t+256, t+512

    __shared__ float part[4][K * D]; // 48 KB: per-stripe partial sums
    __shared__ int   ssep[K];
    __shared__ float sinv[K];

    if (tid < K) {
        int se   = sep[sent * K + tid];
        int prev = (tid == 0) ? 0 : sep[sent * K + tid - 1];
        ssep[tid] = se;
        sinv[tid] = 1.0f / (float)(se - prev - 1);   // span length >= 4
    }
    __syncthreads();

    const int s0 = ssep[0], s1 = ssep[1], s2 = ssep[2], s3 = ssep[3];
    const float* zrow = Z + (size_t)sent * L * D;

    // ---- balanced masked pool: stripes stride the whole token range ----
    float a00=0.f,a01=0.f,a02=0.f, a10=0.f,a11=0.f,a12=0.f;
    float a20=0.f,a21=0.f,a22=0.f, a30=0.f,a31=0.f,a32=0.f;

    for (int l = 1 + s; l < s3; l += 4) {
        const float* r = zrow + (size_t)l * D + t;
        float v0 = r[0], v1 = r[256], v2 = r[512];
        bool m0 = (l < s0);                 // entity 0: [1, s0)
        bool m1 = (l > s0) & (l < s1);      // entity 1: (s0, s1)
        bool m2 = (l > s1) & (l < s2);      // entity 2: (s1, s2)
        bool m3 = (l > s2);                 // entity 3: (s2, s3) via loop bound
        a00 += m0 ? v0 : 0.f; a01 += m0 ? v1 : 0.f; a02 += m0 ? v2 : 0.f;
        a10 += m1 ? v0 : 0.f; a11 += m1 ? v1 : 0.f; a12 += m1 ? v2 : 0.f;
        a20 += m2 ? v0 : 0.f; a21 += m2 ? v1 : 0.f; a22 += m2 ? v2 : 0.f;
        a30 += m3 ? v0 : 0.f; a31 += m3 ? v1 : 0.f; a32 += m3 ? v2 : 0.f;
    }

    float* ps = part[s];
    ps[0*D + t] = a00; ps[0*D + t + 256] = a01; ps[0*D + t + 512] = a02;
    ps[1*D + t] = a10; ps[1*D + t + 256] = a11; ps[1*D + t + 512] = a12;
    ps[2*D + t] = a20; ps[2*D + t + 256] = a21; ps[2*D + t + 512] = a22;
    ps[3*D + t] = a30; ps[3*D + t + 256] = a31; ps[3*D + t + 512] = a32;
    __syncthreads();

    // ---- reduce stripes + scale; result lands in part[0] (unique i per thread) ----
    #pragma unroll
    for (int rr = 0; rr < 3; ++rr) {
        int i = tid + rr * 1024;             // i in [0, 3072)
        float v = part[0][i] + part[1][i] + part[2][i] + part[3][i];
        int e = i / D;                        // const-div -> magic mul
        part[0][i] = v * sinv[e];
    }
    __syncthreads();

    // ---- GEMM: thread = (entity e, col); W shared 4x across e-groups via L1 ----
    const int e   = tid >> 8;
    const int col = tid & 255;
    const float* p = part[0] + e * D;         // LDS broadcast reads
    float o = bias[col];
    #pragma unroll 8
    for (int d = 0; d < D; ++d) {
        o += p[d] * W[d * OUT + col];         // coalesced 256B/wave, L1-reused
    }
    out[(size_t)(sent * K + e) * OUT + col] = o;
}

extern "C" void kernel_launch(void* const* d_in, const int* in_sizes, int n_in,
                              void* d_out, int out_size, void* d_ws, size_t ws_size,
                              hipStream_t stream) {
    const float* Z    = (const float*)d_in[0];
    const int*   sep  = (const int*)d_in[1];
    const float* W    = (const float*)d_in[2];
    const float* bias = (const float*)d_in[3];
    float*       out  = (float*)d_out;

    entity_fused_kernel<<<BS * J, 1024, 0, stream>>>(Z, sep, W, bias, out);
}

// Round 4
// 30.699 us; speedup vs baseline: 1.8150x; 1.8150x over previous
//
#include <hip/hip_runtime.h>
#include <hip/hip_bf16.h>

#define BS  32
#define J   4
#define L   512
#define D   768
#define K   4
#define OUT 256
// entity e = b*16 + j*4 + k  (reference reshape order), e in [0,512)

typedef float f4 __attribute__((ext_vector_type(4)));

// ---------------- Kernel A: ragged span mean-pool ----------------
// 512 blocks (one entity) x 512 threads (8 waves). Wave w processes tokens
// start+w, start+w+8, ... ; each token row = 3 x float4 loads (lane*4 within
// 256-float thirds). LDS 8-way reduce -> pooled[e][768] (already scaled).
__global__ __launch_bounds__(512) void pool_kernel(
    const float* __restrict__ Z,      // [BS,J,L,D]
    const int*   __restrict__ sep,    // [BS,J,K]
    float*       __restrict__ pooled) // [512, D] ws
{
    const int e = blockIdx.x;
    const int b = e >> 4, j = (e >> 2) & 3, k = e & 3;
    const int sbase = (b * J + j) * K;
    const int end   = sep[sbase + k];
    const int prev  = (k == 0) ? 0 : sep[sbase + k - 1];
    const int start = prev + 1;
    const float inv = 1.0f / (float)(end - start);

    const int w    = threadIdx.x >> 6;
    const int lane = threadIdx.x & 63;
    const float* zbase = Z + (size_t)(b * J + j) * L * D + lane * 4;

    f4 a0 = {0,0,0,0}, a1 = {0,0,0,0}, a2 = {0,0,0,0};
    f4 b0 = {0,0,0,0}, b1 = {0,0,0,0}, b2 = {0,0,0,0};

    int l = start + w;
    for (; l + 8 < end; l += 16) {            // two tokens per iter: 6 loads in flight
        const float* r0 = zbase + (size_t)l * D;
        const float* r1 = zbase + (size_t)(l + 8) * D;
        a0 += *(const f4*)(r0);
        a1 += *(const f4*)(r0 + 256);
        a2 += *(const f4*)(r0 + 512);
        b0 += *(const f4*)(r1);
        b1 += *(const f4*)(r1 + 256);
        b2 += *(const f4*)(r1 + 512);
    }
    if (l < end) {
        const float* r0 = zbase + (size_t)l * D;
        a0 += *(const f4*)(r0);
        a1 += *(const f4*)(r0 + 256);
        a2 += *(const f4*)(r0 + 512);
    }
    a0 += b0; a1 += b1; a2 += b2;

    __shared__ float part[8][D];              // 24 KB
    *(f4*)&part[w][lane * 4]       = a0;
    *(f4*)&part[w][lane * 4 + 256] = a1;
    *(f4*)&part[w][lane * 4 + 512] = a2;
    __syncthreads();

    const int t = threadIdx.x;
    if (t < 192) {                            // 192 float4s = 768 floats
        f4 s = {0,0,0,0};
        #pragma unroll
        for (int ww = 0; ww < 8; ++ww) s += *(const f4*)&part[ww][t * 4];
        s *= inv;
        *(f4*)&pooled[(size_t)e * D + t * 4] = s;
    }
}

// ---------------- Kernel B: [512,768] @ [768,256] + bias ----------------
// 512 blocks = (sentence g, col-quarter cq). Block stages 4 pooled rows in LDS.
// 256 threads = (dpar wave in [0,4)) x (lane col in [0,64)); wave owns d-chunk
// of 192: per d: 1 coalesced W load + 4 LDS broadcasts + 4 FMA. Cross-wave
// LDS reduce, add bias, store.
__global__ __launch_bounds__(256) void gemm_kernel(
    const float* __restrict__ pooled, // [512, D]
    const float* __restrict__ W,      // [D, OUT]
    const float* __restrict__ bias,   // [OUT]
    float*       __restrict__ out)    // [512, OUT]
{
    const int g  = blockIdx.x >> 2;   // sentence 0..127
    const int cq = blockIdx.x & 3;    // col quarter

    __shared__ float p[K * D];        // 12 KB
    const float* src = pooled + (size_t)g * K * D;
    for (int i = threadIdx.x; i < (K * D) / 4; i += 256)
        *(f4*)&p[i * 4] = *(const f4*)&src[i * 4];
    __syncthreads();

    const int dpar = threadIdx.x >> 6;        // wave id = d-chunk
    const int lane = threadIdx.x & 63;
    const int col  = cq * 64 + lane;
    const int d0   = dpar * 192;

    float acc0 = 0.f, acc1 = 0.f, acc2 = 0.f, acc3 = 0.f;
    #pragma unroll 4
    for (int d = d0; d < d0 + 192; ++d) {
        float wv = W[d * OUT + col];          // 256B/wave, L2-resident
        acc0 += p[0 * D + d] * wv;            // LDS broadcasts (vectorize to b128)
        acc1 += p[1 * D + d] * wv;
        acc2 += p[2 * D + d] * wv;
        acc3 += p[3 * D + d] * wv;
    }

    __shared__ float red[4][K][64];           // 4 KB
    red[dpar][0][lane] = acc0;
    red[dpar][1][lane] = acc1;
    red[dpar][2][lane] = acc2;
    red[dpar][3][lane] = acc3;
    __syncthreads();

    if (threadIdx.x < 64) {
        #pragma unroll
        for (int e2 = 0; e2 < K; ++e2) {
            float o = red[0][e2][lane] + red[1][e2][lane]
                    + red[2][e2][lane] + red[3][e2][lane] + bias[col];
            out[(size_t)(g * K + e2) * OUT + col] = o;
        }
    }
}

extern "C" void kernel_launch(void* const* d_in, const int* in_sizes, int n_in,
                              void* d_out, int out_size, void* d_ws, size_t ws_size,
                              hipStream_t stream) {
    const float* Z    = (const float*)d_in[0];
    const int*   sep  = (const int*)d_in[1];
    const float* W    = (const float*)d_in[2];
    const float* bias = (const float*)d_in[3];
    float*       out  = (float*)d_out;
    float*       pooled = (float*)d_ws;       // 512*768*4 = 1.5 MB scratch

    pool_kernel<<<BS * J * K, 512, 0, stream>>>(Z, sep, pooled);
    gemm_kernel<<<BS * J * K, 256, 0, stream>>>(pooled, W, bias, out);
}

// Round 5
// 23.011 us; speedup vs baseline: 2.4214x; 1.3341x over previous
//
#include <hip/hip_runtime.h>
#include <hip/hip_bf16.h>

#define BS  32
#define J   4
#define L   512
#define D   768
#define K   4
#define OUT 256
// entity e = b*16 + j*4 + k (reference reshape order); sentence = e>>2 (128)

typedef float f4 __attribute__((ext_vector_type(4)));

// ---------------- Kernel A: ragged span mean-pool (half-span blocks) --------
// 1024 blocks = entity e (512) x half h (2); 256 threads = 4 waves.
// Block (e,h) accumulates tokens l = start + h + 2*(w + 4*i)  (stride-2
// interleave between halves, stride-8 between waves). Scales by 1/count and
// writes a partial row to ws[sent][h][ent][768]; GEMM sums the two halves.
__global__ __launch_bounds__(256) void pool_kernel(
    const float* __restrict__ Z,    // [BS,J,L,D]
    const int*   __restrict__ sep,  // [BS,J,K]
    float*       __restrict__ ws)   // [128][2][4][768]
{
    const int blk  = blockIdx.x;
    const int e    = blk >> 1, h = blk & 1;
    const int sent = e >> 2;        // b*J + j
    const int k    = e & 3;
    const int end   = sep[sent * K + k];
    const int prev  = (k == 0) ? 0 : sep[sent * K + k - 1];
    const int start = prev + 1;
    const float inv = 1.0f / (float)(end - start);

    const int w    = threadIdx.x >> 6;
    const int lane = threadIdx.x & 63;
    const float* zbase = Z + (size_t)sent * L * D + lane * 4;

    f4 a0={0,0,0,0}, a1={0,0,0,0}, a2={0,0,0,0};
    f4 c0={0,0,0,0}, c1={0,0,0,0}, c2={0,0,0,0};

    int l = start + h + 2 * w;                 // this wave's tokens: stride 8
    for (; l + 8 < end; l += 16) {             // 2 tokens/iter: 6 loads in flight
        const float* r0 = zbase + (size_t)l * D;
        const float* r1 = zbase + (size_t)(l + 8) * D;
        a0 += *(const f4*)(r0);       a1 += *(const f4*)(r0 + 256);
        a2 += *(const f4*)(r0 + 512);
        c0 += *(const f4*)(r1);       c1 += *(const f4*)(r1 + 256);
        c2 += *(const f4*)(r1 + 512);
    }
    if (l < end) {
        const float* r0 = zbase + (size_t)l * D;
        a0 += *(const f4*)(r0);       a1 += *(const f4*)(r0 + 256);
        a2 += *(const f4*)(r0 + 512);
    }
    a0 += c0; a1 += c1; a2 += c2;

    __shared__ float part[4][D];               // 12 KB
    *(f4*)&part[w][lane*4]       = a0;
    *(f4*)&part[w][lane*4 + 256] = a1;
    *(f4*)&part[w][lane*4 + 512] = a2;
    __syncthreads();

    const int t = threadIdx.x;
    if (t < 192) {                             // 192 f4 = 768 floats
        f4 s = {0,0,0,0};
        #pragma unroll
        for (int ww = 0; ww < 4; ++ww) s += *(const f4*)&part[ww][t*4];
        s *= inv;
        *(f4*)&ws[(((size_t)sent*2 + h)*K + k) * D + t*4] = s;
    }
}

// ---------------- Kernel B: [512,768] @ [768,256] + bias --------------------
// 512 blocks = (sentence g, col-quarter cq); 256 threads.
// Stage: p[e][d] = ws[g][0][e][d] + ws[g][1][e][d]  (sum of scaled halves).
// Compute: wave w owns d-chunk of 192; lane = (dg,cl): dg picks d = w*192+dg+4i
// (consecutive d across dg -> conflict-free LDS broadcast), cl picks a float4
// of output cols -> 16B coalesced W loads, 16 FMA/load.
__global__ __launch_bounds__(256) void gemm_kernel(
    const float* __restrict__ ws,   // [128][2][4][768]
    const float* __restrict__ W,    // [D, OUT]
    const float* __restrict__ bias, // [OUT]
    float*       __restrict__ out)  // [512, OUT]
{
    const int g  = blockIdx.x >> 2;
    const int cq = blockIdx.x & 3;

    __shared__ float p[K * D];                 // 12 KB
    __shared__ float red[16][K][64];           // 16 KB
    {
        const f4* a = (const f4*)(ws + (size_t)g * 2 * K * D);
        #pragma unroll
        for (int i = threadIdx.x; i < (K * D) / 4; i += 256) {
            f4 v = a[i] + a[i + (K * D) / 4];
            *(f4*)&p[i * 4] = v;
        }
    }
    __syncthreads();

    const int w    = threadIdx.x >> 6;
    const int lane = threadIdx.x & 63;
    const int dg   = lane >> 4;
    const int cl   = lane & 15;
    const int colbase = cq * 64 + cl * 4;
    const int dbase   = w * 192 + dg;

    f4 acc0={0,0,0,0}, acc1={0,0,0,0}, acc2={0,0,0,0}, acc3={0,0,0,0};
    #pragma unroll 4
    for (int i = 0; i < 48; ++i) {
        const int d = dbase + 4 * i;
        f4 wv = *(const f4*)&W[(size_t)d * OUT + colbase];   // 16B coalesced
        acc0 += p[0 * D + d] * wv;             // LDS broadcast within dg group
        acc1 += p[1 * D + d] * wv;
        acc2 += p[2 * D + d] * wv;
        acc3 += p[3 * D + d] * wv;
    }

    const int r = w * 4 + dg;
    *(f4*)&red[r][0][cl * 4] = acc0;
    *(f4*)&red[r][1][cl * 4] = acc1;
    *(f4*)&red[r][2][cl * 4] = acc2;
    *(f4*)&red[r][3][cl * 4] = acc3;
    __syncthreads();

    const int e2  = threadIdx.x >> 6;          // entity
    const int col = threadIdx.x & 63;          // col within quarter
    float s = bias[cq * 64 + col];
    #pragma unroll
    for (int rr = 0; rr < 16; ++rr) s += red[rr][e2][col];  // conflict-free
    out[(size_t)(g * K + e2) * OUT + cq * 64 + col] = s;
}

extern "C" void kernel_launch(void* const* d_in, const int* in_sizes, int n_in,
                              void* d_out, int out_size, void* d_ws, size_t ws_size,
                              hipStream_t stream) {
    const float* Z    = (const float*)d_in[0];
    const int*   sep  = (const int*)d_in[1];
    const float* W    = (const float*)d_in[2];
    const float* bias = (const float*)d_in[3];
    float*       out  = (float*)d_out;
    float*       ws   = (float*)d_ws;          // 128*2*4*768*4 = 3 MB scratch

    pool_kernel<<<2 * BS * J * K, 256, 0, stream>>>(Z, sep, ws);
    gemm_kernel<<<BS * J * K, 256, 0, stream>>>(ws, W, bias, out);
}